// Round 4
// baseline (1669.416 us; speedup 1.0000x reference)
//
#include <hip/hip_runtime.h>
#include <math.h>

#define FN 128      // F_NODE
#define FE 64       // F_EDGE
#define EPS 1e-5f

typedef __attribute__((ext_vector_type(8))) short bf16x8;
typedef __attribute__((ext_vector_type(4))) float f32x4;

__device__ __forceinline__ float bf2f(unsigned int u_low16) {
    union { unsigned int i; float f; } v; v.i = u_low16 << 16; return v.f;
}
__device__ __forceinline__ float bf2f_hi(unsigned int u) {
    union { unsigned int i; float f; } v; v.i = u & 0xffff0000u; return v.f;
}
__device__ __forceinline__ unsigned short f2bf(float f) {
    union { float f; unsigned int i; } v; v.f = f;
    unsigned int r = v.i + 0x7FFFu + ((v.i >> 16) & 1u);
    return (unsigned short)(r >> 16);
}
__device__ __forceinline__ unsigned int pack2bf(float a, float b) {
    return (unsigned int)f2bf(a) | ((unsigned int)f2bf(b) << 16);
}
// fast sigmoid(f) * softplus(s)
__device__ __forceinline__ float actfn(float f, float s) {
    float sig = __builtin_amdgcn_rcpf(1.0f + __expf(-f));
    float sp = fmaxf(s, 0.0f) + __logf(1.0f + __expf(-fabsf(s)));
    return sig * sp;
}

// ---------------------------------------------------------------------------
__global__ void count_kernel(const int* __restrict__ edst, float* __restrict__ cnt, int ne) {
    int e = blockIdx.x * 256 + threadIdx.x;
    if (e < ne) atomicAdd(&cnt[edst[e]], 1.0f);
}

// ---------------------------------------------------------------------------
// Node GEMM: A[n, 512] = X[n,128] @ [Wf(0:128) | Wf(128:256) | Ws(0:128) | Ws(128:256)]
// ---------------------------------------------------------------------------
__global__ __launch_bounds__(256) void node_gemm(
    const float* __restrict__ X, const float* __restrict__ Wf,
    const float* __restrict__ Ws, unsigned short* __restrict__ A, int nnodes)
{
    __shared__ float Xs[16][129];
    __shared__ float Bs[16][68];
    const int t = threadIdx.x;
    const int m0 = blockIdx.x * 128;
    const int c0 = blockIdx.y * 64;
    const int part = c0 >> 7;
    const int cp0 = c0 & 127;
    const float* Bsrc = ((part < 2) ? Wf : Ws) + (part & 1) * 128 * 128 + cp0;
    const int tm = t >> 4, tn = t & 15;
    float acc[8][4];
#pragma unroll
    for (int i = 0; i < 8; i++)
#pragma unroll
        for (int j = 0; j < 4; j++) acc[i][j] = 0.0f;

    for (int k0 = 0; k0 < 128; k0 += 16) {
        {
            int ml = t & 127;
            int kq0 = (t >> 7) * 2;
#pragma unroll
            for (int q = 0; q < 2; q++) {
                int kq = kq0 + q;
                float4 v = make_float4(0.f, 0.f, 0.f, 0.f);
                int m = m0 + ml;
                if (m < nnodes) v = *(const float4*)(X + (size_t)m * FN + k0 + kq * 4);
                Xs[kq * 4 + 0][ml] = v.x; Xs[kq * 4 + 1][ml] = v.y;
                Xs[kq * 4 + 2][ml] = v.z; Xs[kq * 4 + 3][ml] = v.w;
            }
            int kk = t >> 4, j4 = (t & 15) * 4;
            float4 b = *(const float4*)(Bsrc + (size_t)(k0 + kk) * FN + j4);
            Bs[kk][j4 + 0] = b.x; Bs[kk][j4 + 1] = b.y;
            Bs[kk][j4 + 2] = b.z; Bs[kk][j4 + 3] = b.w;
        }
        __syncthreads();
#pragma unroll
        for (int kk = 0; kk < 16; kk++) {
            float xv[8], bv[4];
#pragma unroll
            for (int i = 0; i < 8; i++) xv[i] = Xs[kk][tm * 8 + i];
#pragma unroll
            for (int j = 0; j < 4; j++) bv[j] = Bs[kk][tn * 4 + j];
#pragma unroll
            for (int i = 0; i < 8; i++)
#pragma unroll
                for (int j = 0; j < 4; j++) acc[i][j] = fmaf(xv[i], bv[j], acc[i][j]);
        }
        __syncthreads();
    }
#pragma unroll
    for (int i = 0; i < 8; i++) {
        int m = m0 + tm * 8 + i;
        if (m < nnodes) {
            size_t base = (size_t)m * 512 + c0 + tn * 4;
#pragma unroll
            for (int j = 0; j < 4; j++) A[base + j] = f2bf(acc[i][j]);
        }
    }
}

// ---------------------------------------------------------------------------
// Fused edge kernel, v3: everything in MFMA C-layout, per-wave Ebuf (msg only),
// NO block barriers in the chunk loop.
// Wave owns 64 edges.  C layout of mfma_f32_16x16x32_bf16:
//   edge = nt*16 + (lane&15),  out col = c0 + mt*16 + (lane>>4)*4 + r.
// ---------------------------------------------------------------------------
__global__ __launch_bounds__(256, 2) void edge_kernel(
    const unsigned short* __restrict__ A, const float* __restrict__ EA,
    const int* __restrict__ esrc, const int* __restrict__ edst,
    const float* __restrict__ Wf, const float* __restrict__ Ws,
    const float* __restrict__ bfv, const float* __restrict__ bsv,
    float* __restrict__ summed, int nedges)
{
    __shared__ unsigned short Wlds[2][128][64];  // [mat][outcol][k ^ ((col&7)<<3)] 32 KB
    __shared__ unsigned short Ebuf[4][64][36];   // [wave][edge][col] bf16 msg, 18 KB

    const int t = threadIdx.x;
    const int w = t >> 6, lane = t & 63;
    const int ebase = blockIdx.x * 256 + w * 64;

    // ---- stage We^T (rows 256..319 of Wf/Ws), bf16, XOR-swizzled, paired writes ----
    {
        int col = t & 127;
        int half = t >> 7;                   // 0/1
        int swz = (col & 7) << 3;            // flips bits 3..5 of k index (keeps pairs)
#pragma unroll 2
        for (int mat = 0; mat < 2; mat++) {
            const float* Wsrc = (mat == 0 ? Wf : Ws) + 256 * FN + col;
#pragma unroll
            for (int q = 0; q < 16; q++) {
                int k = half * 32 + q * 2;
                unsigned int u = pack2bf(Wsrc[(size_t)k * FN], Wsrc[(size_t)(k + 1) * FN]);
                *(unsigned int*)&Wlds[mat][col][k ^ swz] = u;
            }
        }
    }

    int e = ebase + lane;
    bool valid = (e < nedges);
    int eC = valid ? e : (nedges - 1);
    const int mydst = edst[eC];
    const int mysrc = esrc[eC];

    // per-nt indices in C-layout (edge = nt*16 + (lane&15))
    int vmask[4];
    const unsigned short* dB[4];
    const unsigned short* sB[4];
#pragma unroll
    for (int nt = 0; nt < 4; nt++) {
        int el = nt * 16 + (lane & 15);
        vmask[nt] = (ebase + el < nedges) ? 1 : 0;
        int dn = __shfl(mydst, el);
        int sn = __shfl(mysrc, el);
        dB[nt] = A + (size_t)dn * 512;
        sB[nt] = A + (size_t)sn * 512 + 128;
    }

    // ---- EA fragments (B operand) ----
    bf16x8 Eb[4][2];
    {
        const int koff = (lane >> 4) << 3;
#pragma unroll
        for (int nt = 0; nt < 4; nt++) {
            int row = ebase + nt * 16 + (lane & 15);
            if (row >= nedges) row = nedges - 1;
            const float* p = EA + (size_t)row * FE + koff;
#pragma unroll
            for (int kk = 0; kk < 2; kk++) {
                float4 v0 = *(const float4*)(p + kk * 32);
                float4 v1 = *(const float4*)(p + kk * 32 + 4);
                bf16x8 b;
                b[0] = (short)f2bf(v0.x); b[1] = (short)f2bf(v0.y);
                b[2] = (short)f2bf(v0.z); b[3] = (short)f2bf(v0.w);
                b[4] = (short)f2bf(v1.x); b[5] = (short)f2bf(v1.y);
                b[6] = (short)f2bf(v1.z); b[7] = (short)f2bf(v1.w);
                Eb[nt][kk] = b;
            }
        }
    }
    __syncthreads();   // Wlds ready — the ONLY block barrier

    const int colo = (lane >> 4) << 2;   // 0,4,8,12

#pragma unroll 1
    for (int cb = 0; cb < 4; cb++) {
        const int c0 = cb * 32;

        // ---- issue A-table gathers (b64, immediate offsets) ----
        uint2 gdf[4][2], gsf[4][2], gds[4][2], gss[4][2];
#pragma unroll
        for (int nt = 0; nt < 4; nt++)
#pragma unroll
            for (int mt = 0; mt < 2; mt++) {
                int off = c0 + mt * 16 + colo;
                gdf[nt][mt] = *(const uint2*)(const void*)(dB[nt] + off);
                gsf[nt][mt] = *(const uint2*)(const void*)(sB[nt] + off);
                gds[nt][mt] = *(const uint2*)(const void*)(dB[nt] + 256 + off);
                gss[nt][mt] = *(const uint2*)(const void*)(sB[nt] + 256 + off);
            }

        // ---- bias ----
        float4 bF[2], bS[2];
#pragma unroll
        for (int mt = 0; mt < 2; mt++) {
            bF[mt] = *(const float4*)(bfv + c0 + mt * 16 + colo);
            bS[mt] = *(const float4*)(bsv + c0 + mt * 16 + colo);
        }

        // ---- MFMA (acc initialized with bias) ----
        f32x4 accF[2][4], accS[2][4];
#pragma unroll
        for (int mt = 0; mt < 2; mt++)
#pragma unroll
            for (int nt = 0; nt < 4; nt++) {
                accF[mt][nt] = (f32x4){bF[mt].x, bF[mt].y, bF[mt].z, bF[mt].w};
                accS[mt][nt] = (f32x4){bS[mt].x, bS[mt].y, bS[mt].z, bS[mt].w};
            }
#pragma unroll
        for (int kk = 0; kk < 2; kk++) {
            bf16x8 aF[2], aS[2];
#pragma unroll
            for (int mt = 0; mt < 2; mt++) {
                int col = c0 + mt * 16 + (lane & 15);
                int kidx = ((kk << 5) + ((lane >> 4) << 3)) ^ ((col & 7) << 3);
                aF[mt] = *(const bf16x8*)&Wlds[0][col][kidx];
                aS[mt] = *(const bf16x8*)&Wlds[1][col][kidx];
            }
#pragma unroll
            for (int mt = 0; mt < 2; mt++)
#pragma unroll
                for (int nt = 0; nt < 4; nt++) {
                    accF[mt][nt] = __builtin_amdgcn_mfma_f32_16x16x32_bf16(
                        aF[mt], Eb[nt][kk], accF[mt][nt], 0, 0, 0);
                    accS[mt][nt] = __builtin_amdgcn_mfma_f32_16x16x32_bf16(
                        aS[mt], Eb[nt][kk], accS[mt][nt], 0, 0, 0);
                }
        }

        // ---- gather-add + activation + msg write (all in C-layout) ----
#pragma unroll
        for (int nt = 0; nt < 4; nt++) {
            int edge = nt * 16 + (lane & 15);
#pragma unroll
            for (int mt = 0; mt < 2; mt++) {
                f32x4 F = accF[mt][nt], S = accS[mt][nt];
                uint2 a0 = gdf[nt][mt], a1 = gsf[nt][mt];
                uint2 b0 = gds[nt][mt], b1 = gss[nt][mt];
                F[0] += bf2f(a0.x & 0xffffu) + bf2f(a1.x & 0xffffu);
                F[1] += bf2f_hi(a0.x)        + bf2f_hi(a1.x);
                F[2] += bf2f(a0.y & 0xffffu) + bf2f(a1.y & 0xffffu);
                F[3] += bf2f_hi(a0.y)        + bf2f_hi(a1.y);
                S[0] += bf2f(b0.x & 0xffffu) + bf2f(b1.x & 0xffffu);
                S[1] += bf2f_hi(b0.x)        + bf2f_hi(b1.x);
                S[2] += bf2f(b0.y & 0xffffu) + bf2f(b1.y & 0xffffu);
                S[3] += bf2f_hi(b0.y)        + bf2f_hi(b1.y);
                float m0 = actfn(F[0], S[0]);
                float m1 = actfn(F[1], S[1]);
                float m2 = actfn(F[2], S[2]);
                float m3 = actfn(F[3], S[3]);
                if (!vmask[nt]) { m0 = m1 = m2 = m3 = 0.0f; }
                uint2 mw = make_uint2(pack2bf(m0, m1), pack2bf(m2, m3));
                *(uint2*)&Ebuf[w][edge][mt * 16 + colo] = mw;
            }
        }
        // wave-local LDS dependence: compiler inserts lgkmcnt before reads below

        // ---- wave-coalesced atomic scatter: 4 edges x (16 lanes x 2 cols) ----
#pragma unroll 4
        for (int it = 0; it < 16; it++) {
            int e2 = (it << 2) + (lane >> 4);
            int cc2 = (lane & 15) << 1;
            int d2 = __shfl(mydst, e2);
            unsigned int u = *(const unsigned int*)&Ebuf[w][e2][cc2];
            float* p = summed + (size_t)d2 * FN + c0 + cc2;
            atomicAdd(p, bf2f(u & 0xffffu));
            atomicAdd(p + 1, bf2f_hi(u));
        }
    }
}

// ---------------------------------------------------------------------------
__global__ __launch_bounds__(256) void finalize_kernel(
    const float* __restrict__ summed, const float* __restrict__ cnt,
    const float* xin,
    const float* __restrict__ gamma, const float* __restrict__ beta,
    const float* __restrict__ rmean, const float* __restrict__ rvar,
    float* out, int nnodes)
{
    int idx = blockIdx.x * 256 + threadIdx.x;
    if (idx >= nnodes * FN) return;
    int n = idx >> 7, c = idx & (FN - 1);
    float mean = summed[idx] / fmaxf(cnt[n], 1.0f);
    float y = (mean - rmean[c]) * rsqrtf(rvar[c] + EPS) * gamma[c] + beta[c] + xin[idx];
    out[idx] = y;
}

// ---------------------------------------------------------------------------
extern "C" void kernel_launch(void* const* d_in, const int* in_sizes, int n_in,
                              void* d_out, int out_size, void* d_ws, size_t ws_size,
                              hipStream_t stream)
{
    const float* x    = (const float*)d_in[0];
    const int*   eidx = (const int*)d_in[1];
    const float* ea   = (const float*)d_in[2];
    const float* Wf1 = (const float*)d_in[3],  * bf1 = (const float*)d_in[4];
    const float* Ws1 = (const float*)d_in[5],  * bs1 = (const float*)d_in[6];
    const float* g1  = (const float*)d_in[7],  * be1 = (const float*)d_in[8];
    const float* rm1 = (const float*)d_in[9],  * rv1 = (const float*)d_in[10];
    const float* Wf2 = (const float*)d_in[11], * bf2 = (const float*)d_in[12];
    const float* Ws2 = (const float*)d_in[13], * bs2 = (const float*)d_in[14];
    const float* g2  = (const float*)d_in[15], * be2 = (const float*)d_in[16];
    const float* rm2 = (const float*)d_in[17], * rv2 = (const float*)d_in[18];
    float* out = (float*)d_out;

    const int NN = in_sizes[0] / FN;
    const int NE = in_sizes[2] / FE;
    const int* esrc = eidx;
    const int* edst = eidx + NE;

    unsigned short* A  = (unsigned short*)d_ws;                        // NN*512*2
    float* summed      = (float*)((char*)d_ws + (size_t)NN * 512 * 2); // NN*128*4
    float* cnt         = (float*)((char*)summed + (size_t)NN * FN * 4);

    const int egrid = (NE + 255) / 256;
    const int ngrid = (NN + 127) / 128;
    const int fgrid = (NN * FN + 255) / 256;

    (void)hipMemsetAsync(cnt, 0, (size_t)NN * 4, stream);
    (void)hipMemsetAsync(summed, 0, (size_t)NN * FN * 4, stream);
    count_kernel<<<egrid, 256, 0, stream>>>(edst, cnt, NE);

    node_gemm<<<dim3(ngrid, 8), 256, 0, stream>>>(x, Wf1, Ws1, A, NN);
    edge_kernel<<<egrid, 256, 0, stream>>>(A, ea, esrc, edst, Wf1, Ws1, bf1, bs1, summed, NE);
    finalize_kernel<<<fgrid, 256, 0, stream>>>(summed, cnt, x, g1, be1, rm1, rv1, out, NN);

    (void)hipMemsetAsync(summed, 0, (size_t)NN * FN * 4, stream);
    node_gemm<<<dim3(ngrid, 8), 256, 0, stream>>>(out, Wf2, Ws2, A, NN);
    edge_kernel<<<egrid, 256, 0, stream>>>(A, ea, esrc, edst, Wf2, Ws2, bf2, bs2, summed, NE);
    finalize_kernel<<<fgrid, 256, 0, stream>>>(summed, cnt, out, g2, be2, rm2, rv2, out, NN);
}

// Round 5
// 872.858 us; speedup vs baseline: 1.9126x; 1.9126x over previous
//
#include <hip/hip_runtime.h>
#include <math.h>

#define FN 128      // F_NODE
#define FE 64       // F_EDGE
#define EPS 1e-5f

typedef __attribute__((ext_vector_type(8))) short bf16x8;
typedef __attribute__((ext_vector_type(4))) float f32x4;

__device__ __forceinline__ float bf2f(unsigned int u_low16) {
    union { unsigned int i; float f; } v; v.i = u_low16 << 16; return v.f;
}
__device__ __forceinline__ float bf2f_hi(unsigned int u) {
    union { unsigned int i; float f; } v; v.i = u & 0xffff0000u; return v.f;
}
__device__ __forceinline__ unsigned short f2bf(float f) {
    union { float f; unsigned int i; } v; v.f = f;
    unsigned int r = v.i + 0x7FFFu + ((v.i >> 16) & 1u);
    return (unsigned short)(r >> 16);
}
__device__ __forceinline__ unsigned int pack2bf(float a, float b) {
    return (unsigned int)f2bf(a) | ((unsigned int)f2bf(b) << 16);
}
// fast sigmoid(f) * softplus(s)
__device__ __forceinline__ float actfn(float f, float s) {
    float sig = __builtin_amdgcn_rcpf(1.0f + __expf(-f));
    float sp = fmaxf(s, 0.0f) + __logf(1.0f + __expf(-fabsf(s)));
    return sig * sp;
}

// ---------------------------------------------------------------------------
// CSR build: histogram -> single-block exclusive scan -> scatter perm
// ---------------------------------------------------------------------------
__global__ void hist_kernel(const int* __restrict__ edst, int* __restrict__ hist, int ne) {
    int e = blockIdx.x * 256 + threadIdx.x;
    if (e < ne) atomicAdd(&hist[edst[e]], 1);
}

__global__ __launch_bounds__(1024) void scan_kernel(
    const int* __restrict__ hist, int* __restrict__ cursor, int nn)
{
    __shared__ int buf[1024];
    int t = threadIdx.x;
    int per = (nn + 1023) >> 10;
    int lo = t * per, hi = min(lo + per, nn);
    int s = 0;
    for (int i = lo; i < hi; i++) s += hist[i];
    buf[t] = s;
    __syncthreads();
    int incl = s;
    for (int off = 1; off < 1024; off <<= 1) {
        int tmp = (t >= off) ? buf[t - off] : 0;
        __syncthreads();
        incl += tmp;
        buf[t] = incl;
        __syncthreads();
    }
    int run = incl - s;   // exclusive base
    for (int i = lo; i < hi; i++) { cursor[i] = run; run += hist[i]; }
}

__global__ void scatter_kernel(const int* __restrict__ edst, int* __restrict__ cursor,
                               int* __restrict__ perm, int ne)
{
    int e = blockIdx.x * 256 + threadIdx.x;
    if (e < ne) {
        int pos = atomicAdd(&cursor[edst[e]], 1);
        perm[pos] = e;
    }
}

// ---------------------------------------------------------------------------
// Node GEMM: A[n, 512] = X[n,128] @ [Wf(0:128) | Wf(128:256) | Ws(0:128) | Ws(128:256)]
// ---------------------------------------------------------------------------
__global__ __launch_bounds__(256) void node_gemm(
    const float* __restrict__ X, const float* __restrict__ Wf,
    const float* __restrict__ Ws, unsigned short* __restrict__ A, int nnodes)
{
    __shared__ float Xs[16][129];
    __shared__ float Bs[16][68];
    const int t = threadIdx.x;
    const int m0 = blockIdx.x * 128;
    const int c0 = blockIdx.y * 64;
    const int part = c0 >> 7;
    const int cp0 = c0 & 127;
    const float* Bsrc = ((part < 2) ? Wf : Ws) + (part & 1) * 128 * 128 + cp0;
    const int tm = t >> 4, tn = t & 15;
    float acc[8][4];
#pragma unroll
    for (int i = 0; i < 8; i++)
#pragma unroll
        for (int j = 0; j < 4; j++) acc[i][j] = 0.0f;

    for (int k0 = 0; k0 < 128; k0 += 16) {
        {
            int ml = t & 127;
            int kq0 = (t >> 7) * 2;
#pragma unroll
            for (int q = 0; q < 2; q++) {
                int kq = kq0 + q;
                float4 v = make_float4(0.f, 0.f, 0.f, 0.f);
                int m = m0 + ml;
                if (m < nnodes) v = *(const float4*)(X + (size_t)m * FN + k0 + kq * 4);
                Xs[kq * 4 + 0][ml] = v.x; Xs[kq * 4 + 1][ml] = v.y;
                Xs[kq * 4 + 2][ml] = v.z; Xs[kq * 4 + 3][ml] = v.w;
            }
            int kk = t >> 4, j4 = (t & 15) * 4;
            float4 b = *(const float4*)(Bsrc + (size_t)(k0 + kk) * FN + j4);
            Bs[kk][j4 + 0] = b.x; Bs[kk][j4 + 1] = b.y;
            Bs[kk][j4 + 2] = b.z; Bs[kk][j4 + 3] = b.w;
        }
        __syncthreads();
#pragma unroll
        for (int kk = 0; kk < 16; kk++) {
            float xv[8], bv[4];
#pragma unroll
            for (int i = 0; i < 8; i++) xv[i] = Xs[kk][tm * 8 + i];
#pragma unroll
            for (int j = 0; j < 4; j++) bv[j] = Bs[kk][tn * 4 + j];
#pragma unroll
            for (int i = 0; i < 8; i++)
#pragma unroll
                for (int j = 0; j < 4; j++) acc[i][j] = fmaf(xv[i], bv[j], acc[i][j]);
        }
        __syncthreads();
    }
#pragma unroll
    for (int i = 0; i < 8; i++) {
        int m = m0 + tm * 8 + i;
        if (m < nnodes) {
            size_t base = (size_t)m * 512 + c0 + tn * 4;
#pragma unroll
            for (int j = 0; j < 4; j++) A[base + j] = f2bf(acc[i][j]);
        }
    }
}

// ---------------------------------------------------------------------------
// Fused edge kernel, v4: edges pre-sorted by dst via perm[]; MFMA C-layout;
// per-wave Ebuf; run-aggregated scatter (one 32-dword atomic per dst-run).
// ---------------------------------------------------------------------------
__global__ __launch_bounds__(256, 2) void edge_kernel(
    const unsigned short* __restrict__ A, const float* __restrict__ EA,
    const int* __restrict__ esrc, const int* __restrict__ edst,
    const int* __restrict__ perm,
    const float* __restrict__ Wf, const float* __restrict__ Ws,
    const float* __restrict__ bfv, const float* __restrict__ bsv,
    float* __restrict__ summed, int nedges)
{
    __shared__ unsigned short Wlds[2][128][64];  // [mat][outcol][k ^ ((col&7)<<3)] 32 KB
    __shared__ unsigned short Ebuf[4][64][36];   // [wave][edge][col] bf16 msg, 18 KB

    const int t = threadIdx.x;
    const int w = t >> 6, lane = t & 63;
    const int ebase = blockIdx.x * 256 + w * 64;

    // ---- stage We^T (rows 256..319 of Wf/Ws), bf16, XOR-swizzled ----
    {
        int col = t & 127;
        int half = t >> 7;
        int swz = (col & 7) << 3;
#pragma unroll 2
        for (int mat = 0; mat < 2; mat++) {
            const float* Wsrc = (mat == 0 ? Wf : Ws) + 256 * FN + col;
#pragma unroll
            for (int q = 0; q < 16; q++) {
                int k = half * 32 + q * 2;
                unsigned int u = pack2bf(Wsrc[(size_t)k * FN], Wsrc[(size_t)(k + 1) * FN]);
                *(unsigned int*)&Wlds[mat][col][k ^ swz] = u;
            }
        }
    }

    int e = ebase + lane;
    bool valid = (e < nedges);
    int eC = valid ? e : (nedges - 1);
    const int pe = perm[eC];
    const int mydst = edst[pe];
    const int mysrc = esrc[pe];

    // per-nt indices in C-layout (edge = nt*16 + (lane&15))
    int vmask[4];
    const unsigned short* dB[4];
    const unsigned short* sB[4];
#pragma unroll
    for (int nt = 0; nt < 4; nt++) {
        int el = nt * 16 + (lane & 15);
        vmask[nt] = (ebase + el < nedges) ? 1 : 0;
        int dn = __shfl(mydst, el);
        int sn = __shfl(mysrc, el);
        dB[nt] = A + (size_t)dn * 512;
        sB[nt] = A + (size_t)sn * 512 + 128;
    }

    // ---- EA fragments (B operand), rows via perm (shfl from pe) ----
    bf16x8 Eb[4][2];
    {
        const int koff = (lane >> 4) << 3;
#pragma unroll
        for (int nt = 0; nt < 4; nt++) {
            int el = nt * 16 + (lane & 15);
            int pr = __shfl(pe, el);
            const float* p = EA + (size_t)pr * FE + koff;
#pragma unroll
            for (int kk = 0; kk < 2; kk++) {
                float4 v0 = *(const float4*)(p + kk * 32);
                float4 v1 = *(const float4*)(p + kk * 32 + 4);
                bf16x8 b;
                b[0] = (short)f2bf(v0.x); b[1] = (short)f2bf(v0.y);
                b[2] = (short)f2bf(v0.z); b[3] = (short)f2bf(v0.w);
                b[4] = (short)f2bf(v1.x); b[5] = (short)f2bf(v1.y);
                b[6] = (short)f2bf(v1.z); b[7] = (short)f2bf(v1.w);
                Eb[nt][kk] = b;
            }
        }
    }
    __syncthreads();   // Wlds ready — the ONLY block barrier

    const int colo = (lane >> 4) << 2;   // 0,4,8,12

#pragma unroll 1
    for (int cb = 0; cb < 4; cb++) {
        const int c0 = cb * 32;

        // ---- issue A-table gathers ----
        uint2 gdf[4][2], gsf[4][2], gds[4][2], gss[4][2];
#pragma unroll
        for (int nt = 0; nt < 4; nt++)
#pragma unroll
            for (int mt = 0; mt < 2; mt++) {
                int off = c0 + mt * 16 + colo;
                gdf[nt][mt] = *(const uint2*)(const void*)(dB[nt] + off);
                gsf[nt][mt] = *(const uint2*)(const void*)(sB[nt] + off);
                gds[nt][mt] = *(const uint2*)(const void*)(dB[nt] + 256 + off);
                gss[nt][mt] = *(const uint2*)(const void*)(sB[nt] + 256 + off);
            }

        // ---- bias ----
        float4 bF[2], bS[2];
#pragma unroll
        for (int mt = 0; mt < 2; mt++) {
            bF[mt] = *(const float4*)(bfv + c0 + mt * 16 + colo);
            bS[mt] = *(const float4*)(bsv + c0 + mt * 16 + colo);
        }

        // ---- MFMA (acc initialized with bias) ----
        f32x4 accF[2][4], accS[2][4];
#pragma unroll
        for (int mt = 0; mt < 2; mt++)
#pragma unroll
            for (int nt = 0; nt < 4; nt++) {
                accF[mt][nt] = (f32x4){bF[mt].x, bF[mt].y, bF[mt].z, bF[mt].w};
                accS[mt][nt] = (f32x4){bS[mt].x, bS[mt].y, bS[mt].z, bS[mt].w};
            }
#pragma unroll
        for (int kk = 0; kk < 2; kk++) {
            bf16x8 aF[2], aS[2];
#pragma unroll
            for (int mt = 0; mt < 2; mt++) {
                int col = c0 + mt * 16 + (lane & 15);
                int kidx = ((kk << 5) + ((lane >> 4) << 3)) ^ ((col & 7) << 3);
                aF[mt] = *(const bf16x8*)&Wlds[0][col][kidx];
                aS[mt] = *(const bf16x8*)&Wlds[1][col][kidx];
            }
#pragma unroll
            for (int mt = 0; mt < 2; mt++)
#pragma unroll
                for (int nt = 0; nt < 4; nt++) {
                    accF[mt][nt] = __builtin_amdgcn_mfma_f32_16x16x32_bf16(
                        aF[mt], Eb[nt][kk], accF[mt][nt], 0, 0, 0);
                    accS[mt][nt] = __builtin_amdgcn_mfma_f32_16x16x32_bf16(
                        aS[mt], Eb[nt][kk], accS[mt][nt], 0, 0, 0);
                }
        }

        // ---- gather-add + activation + msg write (C-layout) ----
#pragma unroll
        for (int nt = 0; nt < 4; nt++) {
            int edge = nt * 16 + (lane & 15);
#pragma unroll
            for (int mt = 0; mt < 2; mt++) {
                f32x4 F = accF[mt][nt], S = accS[mt][nt];
                uint2 a0 = gdf[nt][mt], a1 = gsf[nt][mt];
                uint2 b0 = gds[nt][mt], b1 = gss[nt][mt];
                F[0] += bf2f(a0.x & 0xffffu) + bf2f(a1.x & 0xffffu);
                F[1] += bf2f_hi(a0.x)        + bf2f_hi(a1.x);
                F[2] += bf2f(a0.y & 0xffffu) + bf2f(a1.y & 0xffffu);
                F[3] += bf2f_hi(a0.y)        + bf2f_hi(a1.y);
                S[0] += bf2f(b0.x & 0xffffu) + bf2f(b1.x & 0xffffu);
                S[1] += bf2f_hi(b0.x)        + bf2f_hi(b1.x);
                S[2] += bf2f(b0.y & 0xffffu) + bf2f(b1.y & 0xffffu);
                S[3] += bf2f_hi(b0.y)        + bf2f_hi(b1.y);
                float m0 = actfn(F[0], S[0]);
                float m1 = actfn(F[1], S[1]);
                float m2 = actfn(F[2], S[2]);
                float m3 = actfn(F[3], S[3]);
                if (!vmask[nt]) { m0 = m1 = m2 = m3 = 0.0f; }
                uint2 mw = make_uint2(pack2bf(m0, m1), pack2bf(m2, m3));
                *(uint2*)&Ebuf[w][edge][mt * 16 + colo] = mw;
            }
        }

        // ---- run-aggregated scatter: edges sorted by dst, so flush one
        //      contiguous 32-dword atomic per dst-run per half-wave ----
        {
            int h = lane >> 5, cc = lane & 31;
            int base_e = h << 5;
            float run = 0.f;
            int prev = __shfl(mydst, base_e);
#pragma unroll 1
            for (int q = 0; q < 32; q++) {
                int e2 = base_e + q;
                int d2 = __shfl(mydst, e2);
                float v = bf2f((unsigned int)Ebuf[w][e2][cc]);
                if (d2 != prev) {
                    atomicAdd(&summed[(size_t)prev * FN + c0 + cc], run);
                    run = 0.f; prev = d2;
                }
                run += v;
            }
            atomicAdd(&summed[(size_t)prev * FN + c0 + cc], run);
        }
    }
}

// ---------------------------------------------------------------------------
__global__ __launch_bounds__(256) void finalize_kernel(
    const float* __restrict__ summed, const int* __restrict__ hist,
    const float* xin,
    const float* __restrict__ gamma, const float* __restrict__ beta,
    const float* __restrict__ rmean, const float* __restrict__ rvar,
    float* out, int nnodes)
{
    int idx = blockIdx.x * 256 + threadIdx.x;
    if (idx >= nnodes * FN) return;
    int n = idx >> 7, c = idx & (FN - 1);
    float cnt = (float)hist[n];
    float mean = summed[idx] / fmaxf(cnt, 1.0f);
    float y = (mean - rmean[c]) * rsqrtf(rvar[c] + EPS) * gamma[c] + beta[c] + xin[idx];
    out[idx] = y;
}

// ---------------------------------------------------------------------------
extern "C" void kernel_launch(void* const* d_in, const int* in_sizes, int n_in,
                              void* d_out, int out_size, void* d_ws, size_t ws_size,
                              hipStream_t stream)
{
    const float* x    = (const float*)d_in[0];
    const int*   eidx = (const int*)d_in[1];
    const float* ea   = (const float*)d_in[2];
    const float* Wf1 = (const float*)d_in[3],  * bf1 = (const float*)d_in[4];
    const float* Ws1 = (const float*)d_in[5],  * bs1 = (const float*)d_in[6];
    const float* g1  = (const float*)d_in[7],  * be1 = (const float*)d_in[8];
    const float* rm1 = (const float*)d_in[9],  * rv1 = (const float*)d_in[10];
    const float* Wf2 = (const float*)d_in[11], * bf2 = (const float*)d_in[12];
    const float* Ws2 = (const float*)d_in[13], * bs2 = (const float*)d_in[14];
    const float* g2  = (const float*)d_in[15], * be2 = (const float*)d_in[16];
    const float* rm2 = (const float*)d_in[17], * rv2 = (const float*)d_in[18];
    float* out = (float*)d_out;

    const int NN = in_sizes[0] / FN;
    const int NE = in_sizes[2] / FE;
    const int* esrc = eidx;
    const int* edst = eidx + NE;

    // workspace layout
    char* wsp = (char*)d_ws;
    unsigned short* A = (unsigned short*)wsp;            wsp += (size_t)NN * 512 * 2; // 51.2 MB
    float* summed     = (float*)wsp;                     wsp += (size_t)NN * FN * 4;  // 25.6 MB
    int* hist         = (int*)wsp;                       wsp += (size_t)NN * 4;       // 0.2 MB
    int* perm         = (int*)wsp;                       wsp += (size_t)NE * 4;       // 3.2 MB
    int* cursor       = (int*)summed;  // overlaid: consumed before summed memset

    const int egrid = (NE + 255) / 256;
    const int ngrid = (NN + 127) / 128;
    const int fgrid = (NN * FN + 255) / 256;

    // ---- CSR build (shared by both layers) ----
    (void)hipMemsetAsync(hist, 0, (size_t)NN * 4, stream);
    hist_kernel<<<egrid, 256, 0, stream>>>(edst, hist, NE);
    scan_kernel<<<1, 1024, 0, stream>>>(hist, cursor, NN);
    scatter_kernel<<<egrid, 256, 0, stream>>>(edst, cursor, perm, NE);

    // ---- layer 1 ----
    (void)hipMemsetAsync(summed, 0, (size_t)NN * FN * 4, stream);
    node_gemm<<<dim3(ngrid, 8), 256, 0, stream>>>(x, Wf1, Ws1, A, NN);
    edge_kernel<<<egrid, 256, 0, stream>>>(A, ea, esrc, edst, perm, Wf1, Ws1, bf1, bs1, summed, NE);
    finalize_kernel<<<fgrid, 256, 0, stream>>>(summed, hist, x, g1, be1, rm1, rv1, out, NN);

    // ---- layer 2 ----
    (void)hipMemsetAsync(summed, 0, (size_t)NN * FN * 4, stream);
    node_gemm<<<dim3(ngrid, 8), 256, 0, stream>>>(out, Wf2, Ws2, A, NN);
    edge_kernel<<<egrid, 256, 0, stream>>>(A, ea, esrc, edst, perm, Wf2, Ws2, bf2, bs2, summed, NE);
    finalize_kernel<<<fgrid, 256, 0, stream>>>(summed, hist, out, g2, be2, rm2, rv2, out, NN);
}